// Round 1
// baseline (2661.244 us; speedup 1.0000x reference)
//
#include <hip/hip_runtime.h>

// Problem constants
#define B_    2
#define CI_   32
#define CO_   64
#define H_    96
#define W_    96
#define D_    35
#define PLANE (H_ * W_ * D_)          // 322560 per (b,co) plane... actually per channel per batch: H*W*D
#define NPC   (B_ * PLANE)            // elements per channel for BN stats: 645120

constexpr int COB = 8;                 // output channels per block
constexpr int NW  = W_ + 2;            // 98 (padded W)
constexpr int ND  = D_ + 2;            // 37 (padded D)
constexpr int ROW = NW * ND;           // 3626
constexpr int IN_TILE = 3 * ROW;       // 10878 floats = 43.5 KB (3 kh rows)
constexpr int WTILE   = COB * CI_ * 27;// 6912 floats = 27.6 KB

// -------- Kernel 0: zero the stats accumulators (graph-capture safe) --------
__global__ void zero_stats(float* stats) {
    if (threadIdx.x < 2 * CO_) stats[threadIdx.x] = 0.0f;
}

// -------- Kernel 1: conv3d + bias, write pre-BN output, accumulate stats ----
// grid: (H, CO/COB, B), block: 512 threads
// thread -> (w = tid/5, dt = tid%5); covers w in [0,96), d in [dt*7, dt*7+7)
__global__ __launch_bounds__(512)
void conv_stats_kernel(const float* __restrict__ x,
                       const float* __restrict__ wg,
                       const float* __restrict__ bias,
                       float* __restrict__ out,
                       float* __restrict__ stats) {
    __shared__ float in_lds[IN_TILE];
    __shared__ float w_lds[WTILE];
    __shared__ float red[8][COB][2];

    const int h   = blockIdx.x;
    const int co0 = blockIdx.y * COB;
    const int b   = blockIdx.z;
    const int tid = threadIdx.x;
    const int w   = tid / 5;        // 0..102 (>=96 inactive)
    const int dt  = tid - 5 * w;    // 0..4
    const int d0  = dt * 7;
    const bool act = (w < W_);

    // stage this block's weights once: w_lds[co][ci][27] contiguous
    for (int idx = tid; idx < WTILE; idx += 512)
        w_lds[idx] = wg[co0 * (CI_ * 27) + idx];

    float acc[COB][7];
    #pragma unroll
    for (int c = 0; c < COB; ++c)
        #pragma unroll
        for (int j = 0; j < 7; ++j) acc[c][j] = 0.0f;

    for (int ci = 0; ci < CI_; ++ci) {
        __syncthreads();  // protect previous tile use (and weights on iter 0)
        // stage padded input slab: rows h-1..h+1, all (w,d) with halo, zeros outside
        const float* xb = x + (size_t)(b * CI_ + ci) * (H_ * W_ * D_);
        for (int idx = tid; idx < IN_TILE; idx += 512) {
            int r   = idx / ROW;
            int rem = idx - r * ROW;
            int lw  = rem / ND;
            int ld  = rem - lw * ND;
            int gh = h + r - 1, gw = lw - 1, gd = ld - 1;
            float v = 0.0f;
            if ((unsigned)gh < (unsigned)H_ && (unsigned)gw < (unsigned)W_ &&
                (unsigned)gd < (unsigned)D_)
                v = xb[(gh * W_ + gw) * D_ + gd];
            in_lds[idx] = v;
        }
        __syncthreads();

        if (act) {
            #pragma unroll
            for (int r = 0; r < 3; ++r) {
                // input values needed for this kh row: 3 kw x 9 d-offsets
                float vals[3][9];
                #pragma unroll
                for (int kw = 0; kw < 3; ++kw) {
                    const int base = r * ROW + (w + kw) * ND + d0;
                    #pragma unroll
                    for (int t = 0; t < 9; ++t) vals[kw][t] = in_lds[base + t];
                }
                #pragma unroll
                for (int c = 0; c < COB; ++c) {
                    const float* wp = &w_lds[(c * CI_ + ci) * 27 + r * 9];
                    #pragma unroll
                    for (int kw = 0; kw < 3; ++kw)
                        #pragma unroll
                        for (int kd = 0; kd < 3; ++kd) {
                            const float wv = wp[kw * 3 + kd];
                            #pragma unroll
                            for (int j = 0; j < 7; ++j)
                                acc[c][j] = fmaf(vals[kw][kd + j], wv, acc[c][j]);
                        }
                }
            }
        }
    }

    // store (conv + bias) and reduce per-channel sum / sumsq
    const int wave = tid >> 6;
    const int lane = tid & 63;
    #pragma unroll
    for (int c = 0; c < COB; ++c) {
        float s1 = 0.0f, s2 = 0.0f;
        if (act) {
            const float bi = bias[co0 + c];
            size_t base = ((((size_t)(b * CO_ + co0 + c) * H_) + h) * W_ + w) * D_ + d0;
            #pragma unroll
            for (int j = 0; j < 7; ++j) {
                float v = acc[c][j] + bi;
                out[base + j] = v;
                s1 += v;
                s2 += v * v;
            }
        }
        #pragma unroll
        for (int off = 32; off > 0; off >>= 1) {
            s1 += __shfl_down(s1, off);
            s2 += __shfl_down(s2, off);
        }
        if (lane == 0) { red[wave][c][0] = s1; red[wave][c][1] = s2; }
    }
    __syncthreads();
    if (tid < COB * 2) {
        const int c = tid >> 1, k = tid & 1;
        float s = 0.0f;
        #pragma unroll
        for (int wv = 0; wv < 8; ++wv) s += red[wv][c][k];
        atomicAdd(&stats[(co0 + c) * 2 + k], s);
    }
}

// -------- Kernel 2: per-channel scale/shift from global sums ----------------
__global__ void finalize_stats(const float* __restrict__ stats,
                               const float* __restrict__ gamma,
                               const float* __restrict__ beta,
                               float* __restrict__ ss) {
    const int c = threadIdx.x;
    if (c < CO_) {
        const float inv = 1.0f / (float)NPC;
        const float mean = stats[c * 2] * inv;
        const float var  = fmaf(-mean, mean, stats[c * 2 + 1] * inv);
        const float scale = gamma[c] * rsqrtf(var + 1e-5f);
        const float shift = fmaf(-mean, scale, beta[c]);
        ss[c * 2]     = scale;
        ss[c * 2 + 1] = shift;
    }
}

// -------- Kernel 3: in-place BN apply + LeakyReLU, float4 ------------------
__global__ __launch_bounds__(256)
void bn_lrelu_kernel(float* __restrict__ out, const float* __restrict__ ss) {
    __shared__ float s_ss[CO_ * 2];
    if (threadIdx.x < CO_ * 2) s_ss[threadIdx.x] = ss[threadIdx.x];
    __syncthreads();
    constexpr int N4 = (B_ * CO_ * PLANE) / 4;   // 10,321,920
    constexpr int P4 = PLANE / 4;                // 80,640 (channel uniform per float4)
    const int stride = gridDim.x * blockDim.x;
    for (int i = blockIdx.x * blockDim.x + threadIdx.x; i < N4; i += stride) {
        float4 v = reinterpret_cast<float4*>(out)[i];
        const int c = (i / P4) & (CO_ - 1);
        const float sc = s_ss[c * 2], sh = s_ss[c * 2 + 1];
        v.x = fmaf(v.x, sc, sh);
        v.y = fmaf(v.y, sc, sh);
        v.z = fmaf(v.z, sc, sh);
        v.w = fmaf(v.w, sc, sh);
        v.x = v.x >= 0.0f ? v.x : 0.2f * v.x;
        v.y = v.y >= 0.0f ? v.y : 0.2f * v.y;
        v.z = v.z >= 0.0f ? v.z : 0.2f * v.z;
        v.w = v.w >= 0.0f ? v.w : 0.2f * v.w;
        reinterpret_cast<float4*>(out)[i] = v;
    }
}

extern "C" void kernel_launch(void* const* d_in, const int* in_sizes, int n_in,
                              void* d_out, int out_size, void* d_ws, size_t ws_size,
                              hipStream_t stream) {
    const float* x     = (const float*)d_in[0];
    const float* wg    = (const float*)d_in[1];
    const float* bias  = (const float*)d_in[2];
    const float* gamma = (const float*)d_in[3];
    const float* beta  = (const float*)d_in[4];
    float* out   = (float*)d_out;
    float* stats = (float*)d_ws;        // 128 floats: per-channel {sum, sumsq}
    float* ss    = stats + 128;         // 128 floats: per-channel {scale, shift}

    zero_stats<<<1, 128, 0, stream>>>(stats);

    dim3 grid1(H_, CO_ / COB, B_);
    conv_stats_kernel<<<grid1, 512, 0, stream>>>(x, wg, bias, out, stats);

    finalize_stats<<<1, 64, 0, stream>>>(stats, gamma, beta, ss);

    bn_lrelu_kernel<<<2048, 256, 0, stream>>>(out, ss);
}

// Round 2
// 875.650 us; speedup vs baseline: 3.0392x; 3.0392x over previous
//
#include <hip/hip_runtime.h>

// Problem constants
#define B_    2
#define CI_   32
#define CO_   64
#define H_    96
#define W_    96
#define D_    35
#define PLANE (H_ * W_ * D_)           // 322560
#define NPC   (B_ * PLANE)             // 645120 elements per channel for BN
#define HWD_  (H_ * W_ * D_)

constexpr int TW  = 6;                 // output w-columns per block
constexpr int PD  = 37;                // padded d pitch (d -1..35)
constexpr int RP  = 300;               // rows per h-plane: 8*37 + 4 guard
constexpr int NFRAG = 14;              // 16-row M fragments (m in [38, 262))
constexpr float NEG = 0.2f;

typedef __attribute__((ext_vector_type(8))) short bf16x8;
typedef __attribute__((ext_vector_type(4))) float f32x4;

__device__ __forceinline__ unsigned short f2bf(float f) {
    unsigned u = __float_as_uint(f);
    u = (u + 0x7FFFu + ((u >> 16) & 1u)) >> 16;   // RNE
    return (unsigned short)u;
}
__device__ __forceinline__ float bf2f(unsigned short h) {
    return __uint_as_float(((unsigned)h) << 16);
}

// -------- Kernel 0: zero the stats accumulators -----------------------------
__global__ void zero_stats(float* stats) {
    if (threadIdx.x < 2 * CO_) stats[threadIdx.x] = 0.0f;
}

// -------- Kernel 1: weight prep: fp32 [co][ci][27] -> bf16 hi/lo [ver][tap][co][ci]
__global__ void prep_w(const float* __restrict__ wg, short* __restrict__ Bg) {
    int idx = blockIdx.x * 256 + threadIdx.x;
    if (idx < 27 * CO_ * CI_) {
        int tap = idx >> 11;            // /2048
        int r   = idx & 2047;
        int co  = r >> 5, ci = r & 31;
        float v = wg[(co * CI_ + ci) * 27 + tap];
        unsigned short hi = f2bf(v);
        unsigned short lo = f2bf(v - bf2f(hi));
        Bg[tap * 2048 + r]              = (short)hi;   // ver 0
        Bg[27 * 2048 + tap * 2048 + r]  = (short)lo;   // ver 1
    }
}

// -------- Kernel 2: MFMA conv + fused BN-stats ------------------------------
// grid (16 wtiles, 96 h, 2 b), 256 threads (4 waves)
__global__ __launch_bounds__(256, 2)
void conv_mfma_kernel(const float* __restrict__ x,
                      const short* __restrict__ Bg,
                      float* __restrict__ out,
                      float* __restrict__ stats) {
    __shared__ short As[3 * RP * 32];          // 57600 B, [kh][m][ci] bf16
    __shared__ short Bs[2][2][CO_ * 32];       // 16384 B, [buf][ver][co][ci]

    const int b   = blockIdx.z;
    const int h   = blockIdx.y;
    const int w0  = blockIdx.x * TW;
    const int tid = threadIdx.x;

    // ---- stage A tile: x -> bf16, layout [kh][m=w'*37+d'][ci], zeros at pads/guards
    for (int u = tid; u < 3 * RP * 4; u += 256) {
        const int kh  = u / (RP * 4);
        const int r2  = u - kh * (RP * 4);
        const int mr  = r2 >> 2;
        const int oct = r2 & 3;
        const int wp  = mr / PD;
        const int dp  = mr - wp * PD;
        const int gh  = h + kh - 1;
        const int gw  = w0 + wp - 1;
        const int gd  = dp - 1;
        const bool vld = ((unsigned)gh < 96u) && (wp < 8) &&
                         ((unsigned)gw < 96u) && ((unsigned)gd < 35u);
        unsigned short h8[8];
        if (vld) {
            const float* xp = x + ((((size_t)b * CI_) * H_ + gh) * W_ + gw) * D_ + gd;
            #pragma unroll
            for (int j = 0; j < 8; ++j)
                h8[j] = f2bf(xp[(size_t)(oct * 8 + j) * HWD_]);
        } else {
            #pragma unroll
            for (int j = 0; j < 8; ++j) h8[j] = 0;
        }
        bf16x8 pk;
        #pragma unroll
        for (int j = 0; j < 8; ++j) pk[j] = (short)h8[j];
        *reinterpret_cast<bf16x8*>(&As[(kh * RP + mr) * 32 + oct * 8]) = pk;
    }

    // ---- stage B tap 0 (hi+lo), double-buffered afterwards
    const uint4* bg = reinterpret_cast<const uint4*>(Bg);  // 16B chunks; ver stride 6912
    {
        uint4 bh = bg[tid];             // tap0 hi
        uint4 bl = bg[6912 + tid];      // tap0 lo
        reinterpret_cast<uint4*>(&Bs[0][0][0])[tid] = bh;
        reinterpret_cast<uint4*>(&Bs[0][1][0])[tid] = bl;
    }
    __syncthreads();

    const int wave = tid >> 6;
    const int ln   = tid & 15;          // row/col within fragment
    const int hk   = (tid >> 4) & 3;    // k-chunk

    f32x4 acc[4][4] = {};               // [m-slot][co-frag]

    for (int t = 0; t < 27; ++t) {
        const int buf = t & 1;
        uint4 nh = {}, nl = {};
        if (t + 1 < 27) {               // prefetch next tap early (T14)
            nh = bg[(t + 1) * 256 + tid];
            nl = bg[6912 + (t + 1) * 256 + tid];
        }
        const int kh = t / 9;
        const int kw = (t / 3) % 3;
        const int kd = t % 3;
        const int shift = (kw - 1) * PD + (kd - 1);

        bf16x8 Bf[4][2];
        #pragma unroll
        for (int n = 0; n < 4; ++n)
            #pragma unroll
            for (int v = 0; v < 2; ++v)
                Bf[n][v] = *reinterpret_cast<const bf16x8*>(
                    &Bs[buf][v][(n * 16 + ln) * 32 + hk * 8]);

        #pragma unroll
        for (int s = 0; s < 4; ++s) {
            const int fi = wave + 4 * s;
            if (fi < NFRAG) {
                const int row = kh * RP + 38 + 16 * fi + shift + ln;
                bf16x8 Af = *reinterpret_cast<const bf16x8*>(&As[row * 32 + hk * 8]);
                #pragma unroll
                for (int n = 0; n < 4; ++n) {
                    acc[s][n] = __builtin_amdgcn_mfma_f32_16x16x32_bf16(Af, Bf[n][0], acc[s][n], 0, 0, 0);
                    acc[s][n] = __builtin_amdgcn_mfma_f32_16x16x32_bf16(Af, Bf[n][1], acc[s][n], 0, 0, 0);
                }
            }
        }

        if (t + 1 < 27) {               // write-late into the other buffer
            reinterpret_cast<uint4*>(&Bs[buf ^ 1][0][0])[tid] = nh;
            reinterpret_cast<uint4*>(&Bs[buf ^ 1][1][0])[tid] = nl;
        }
        __syncthreads();
    }

    // ---- epilogue: store conv output + per-channel sum/sumsq
    float s1[4] = {0.f, 0.f, 0.f, 0.f};
    float s2[4] = {0.f, 0.f, 0.f, 0.f};
    #pragma unroll
    for (int s = 0; s < 4; ++s) {
        const int fi = wave + 4 * s;
        if (fi < NFRAG) {
            const int m0 = 38 + 16 * fi;
            #pragma unroll
            for (int r = 0; r < 4; ++r) {
                const int m  = m0 + hk * 4 + r;
                const int wp = m / PD;
                const int dp = m - wp * PD;
                if (dp >= 1 && dp <= 35 && wp >= 1 && wp <= TW) {
                    const int gw = w0 + wp - 1;
                    const int gd = dp - 1;
                    #pragma unroll
                    for (int n = 0; n < 4; ++n) {
                        const int co = n * 16 + ln;
                        const float vv = acc[s][n][r];
                        out[((((size_t)b * CO_ + co) * H_ + h) * W_ + gw) * D_ + gd] = vv;
                        s1[n] += vv;
                        s2[n] += vv * vv;
                    }
                }
            }
        }
    }
    #pragma unroll
    for (int n = 0; n < 4; ++n) {
        s1[n] += __shfl_xor(s1[n], 16);
        s1[n] += __shfl_xor(s1[n], 32);
        s2[n] += __shfl_xor(s2[n], 16);
        s2[n] += __shfl_xor(s2[n], 32);
    }
    if ((tid & 63) < 16) {
        #pragma unroll
        for (int n = 0; n < 4; ++n) {
            const int co = n * 16 + ln;
            atomicAdd(&stats[co * 2],     s1[n]);
            atomicAdd(&stats[co * 2 + 1], s2[n]);
        }
    }
}

// -------- Kernel 3: per-channel scale/shift ---------------------------------
__global__ void finalize_stats(const float* __restrict__ stats,
                               const float* __restrict__ gamma,
                               const float* __restrict__ beta,
                               float* __restrict__ ss) {
    const int c = threadIdx.x;
    if (c < CO_) {
        const float inv = 1.0f / (float)NPC;
        const float mean = stats[c * 2] * inv;
        const float var  = fmaf(-mean, mean, stats[c * 2 + 1] * inv);
        const float scale = gamma[c] * rsqrtf(var + 1e-5f);
        const float shift = fmaf(-mean, scale, beta[c]);
        ss[c * 2]     = scale;
        ss[c * 2 + 1] = shift;
    }
}

// -------- Kernel 4: in-place BN apply + LeakyReLU, float4 -------------------
__global__ __launch_bounds__(256)
void bn_lrelu_kernel(float* __restrict__ out, const float* __restrict__ ss) {
    __shared__ float s_ss[CO_ * 2];
    if (threadIdx.x < CO_ * 2) s_ss[threadIdx.x] = ss[threadIdx.x];
    __syncthreads();
    constexpr int N4 = (B_ * CO_ * PLANE) / 4;
    constexpr int P4 = PLANE / 4;
    const int stride = gridDim.x * blockDim.x;
    for (int i = blockIdx.x * blockDim.x + threadIdx.x; i < N4; i += stride) {
        float4 v = reinterpret_cast<float4*>(out)[i];
        const int c = (i / P4) & (CO_ - 1);
        const float sc = s_ss[c * 2], sh = s_ss[c * 2 + 1];
        v.x = fmaf(v.x, sc, sh);
        v.y = fmaf(v.y, sc, sh);
        v.z = fmaf(v.z, sc, sh);
        v.w = fmaf(v.w, sc, sh);
        v.x = v.x >= 0.0f ? v.x : NEG * v.x;
        v.y = v.y >= 0.0f ? v.y : NEG * v.y;
        v.z = v.z >= 0.0f ? v.z : NEG * v.z;
        v.w = v.w >= 0.0f ? v.w : NEG * v.w;
        reinterpret_cast<float4*>(out)[i] = v;
    }
}

extern "C" void kernel_launch(void* const* d_in, const int* in_sizes, int n_in,
                              void* d_out, int out_size, void* d_ws, size_t ws_size,
                              hipStream_t stream) {
    const float* x     = (const float*)d_in[0];
    const float* wg    = (const float*)d_in[1];
    // d_in[2] = bias: cancelled exactly by BatchNorm mean subtraction — unused.
    const float* gamma = (const float*)d_in[3];
    const float* beta  = (const float*)d_in[4];
    float* out   = (float*)d_out;

    char*  ws    = (char*)d_ws;
    float* stats = (float*)ws;                  // 128 f32 {sum, sumsq}
    float* ss    = (float*)(ws + 512);          // 128 f32 {scale, shift}
    short* Bg    = (short*)(ws + 1024);         // 2*27*64*32 bf16 = 221184 B

    zero_stats<<<1, 128, 0, stream>>>(stats);
    prep_w<<<(27 * CO_ * CI_ + 255) / 256, 256, 0, stream>>>(wg, Bg);

    dim3 grid(W_ / TW, H_, B_);
    conv_mfma_kernel<<<grid, 256, 0, stream>>>(x, Bg, out, stats);

    finalize_stats<<<1, 64, 0, stream>>>(stats, gamma, beta, ss);
    bn_lrelu_kernel<<<2048, 256, 0, stream>>>(out, ss);
}

// Round 4
// 874.096 us; speedup vs baseline: 3.0446x; 1.0018x over previous
//
#include <hip/hip_runtime.h>

// Problem constants
#define B_    2
#define CI_   32
#define CO_   64
#define H_    96
#define W_    96
#define D_    35
#define PLANE (H_ * W_ * D_)           // 322560
#define NPC   (B_ * PLANE)             // 645120 elements per channel for BN
#define HWD_  (H_ * W_ * D_)

constexpr int TW  = 6;                 // output w-columns per block
constexpr int PD  = 37;                // padded d pitch (d -1..35)
constexpr int RP  = 300;               // rows per h-plane: 8*37 + 4 guard
constexpr int NFRAG = 14;              // 16-row M fragments (m in [38, 262))
constexpr float NEG = 0.2f;

typedef __attribute__((ext_vector_type(8))) short bf16x8;
typedef __attribute__((ext_vector_type(4))) float f32x4;

__device__ __forceinline__ unsigned short f2bf(float f) {
    unsigned u = __float_as_uint(f);
    u = (u + 0x7FFFu + ((u >> 16) & 1u)) >> 16;   // RNE
    return (unsigned short)u;
}
__device__ __forceinline__ float bf2f(unsigned short h) {
    return __uint_as_float(((unsigned)h) << 16);
}

// -------- Kernel 0: zero the stats accumulators -----------------------------
__global__ void zero_stats(float* stats) {
    if (threadIdx.x < 2 * CO_) stats[threadIdx.x] = 0.0f;
}

// -------- Kernel 1: weight prep -> bf16 hi/lo, layout [tap][ver][co][ci] ----
__global__ void prep_w(const float* __restrict__ wg, short* __restrict__ Bg) {
    int idx = blockIdx.x * 256 + threadIdx.x;
    if (idx < 27 * CO_ * CI_) {
        int tap = idx >> 11;            // /2048
        int r   = idx & 2047;
        int co  = r >> 5, ci = r & 31;
        float v = wg[(co * CI_ + ci) * 27 + tap];
        unsigned short hi = f2bf(v);
        unsigned short lo = f2bf(v - bf2f(hi));
        Bg[(tap * 2 + 0) * 2048 + r] = (short)hi;
        Bg[(tap * 2 + 1) * 2048 + r] = (short)lo;
    }
}

// -------- Kernel 2: MFMA conv + fused BN-stats ------------------------------
// grid (16 wtiles, 96 h, 2 b), 256 threads (4 waves)
// A staged ONCE in LDS (one barrier); B read global->reg per tap, no barriers
// in the 27-tap loop. LDS layout: 16B chunks [kh][ci_oct][m] -> each 16-lane
// read phase is 256B contiguous (conflict-free).
__global__ __launch_bounds__(256, 2)
void conv_mfma_kernel(const float* __restrict__ x,
                      const short* __restrict__ Bg,
                      float* __restrict__ out,
                      float* __restrict__ stats) {
    __shared__ short As[3 * 4 * RP * 8];       // 57600 B

    const int b   = blockIdx.z;
    const int h   = blockIdx.y;
    const int w0  = blockIdx.x * TW;
    const int tid = threadIdx.x;

    // ---- stage A tile: x -> bf16, chunk = (kh*4+oct)*RP + m, zeros at pads
    for (int u = tid; u < 3 * 4 * RP; u += 256) {
        const int kh  = u / (4 * RP);
        const int r2  = u - kh * (4 * RP);
        const int oct = r2 / RP;
        const int mr  = r2 - oct * RP;
        const int wp  = mr / PD;
        const int dp  = mr - wp * PD;
        const int gh  = h + kh - 1;
        const int gw  = w0 + wp - 1;
        const int gd  = dp - 1;
        const bool vld = ((unsigned)gh < 96u) && (wp < 8) &&
                         ((unsigned)gw < 96u) && ((unsigned)gd < 35u);
        bf16x8 pk;
        if (vld) {
            const float* xp = x + ((((size_t)b * CI_) * H_ + gh) * W_ + gw) * D_ + gd;
            #pragma unroll
            for (int j = 0; j < 8; ++j)
                pk[j] = (short)f2bf(xp[(size_t)(oct * 8 + j) * HWD_]);
        } else {
            #pragma unroll
            for (int j = 0; j < 8; ++j) pk[j] = 0;
        }
        *reinterpret_cast<bf16x8*>(&As[u * 8]) = pk;
    }
    __syncthreads();   // the ONLY barrier

    const int wave = tid >> 6;
    const int ln   = tid & 15;          // fragment row / co-low
    const int hk   = (tid >> 4) & 3;    // k-chunk
    const int pl   = ln * 32 + hk * 8;  // per-lane B offset (shorts)

    f32x4 acc[4][4] = {};               // [m-slot][co-frag]

    bf16x8 bA[4][2], bB[4][2];
    #pragma unroll
    for (int n = 0; n < 4; ++n)
        #pragma unroll
        for (int v = 0; v < 2; ++v)
            bA[n][v] = *reinterpret_cast<const bf16x8*>(Bg + v * 2048 + n * 512 + pl);

    auto body = [&](int t, bf16x8 (&cur)[4][2], bf16x8 (&nxt)[4][2]) {
        if (t < 26) {                   // prefetch next tap's B early (T14)
            const short* bp = Bg + (t + 1) * 4096 + pl;
            #pragma unroll
            for (int n = 0; n < 4; ++n)
                #pragma unroll
                for (int v = 0; v < 2; ++v)
                    nxt[n][v] = *reinterpret_cast<const bf16x8*>(bp + v * 2048 + n * 512);
        }
        const int kh = t / 9;
        const int kw = (t / 3) % 3;
        const int kd = t - kh * 9 - kw * 3;
        const int shift = (kw - 1) * PD + (kd - 1);
        const int cbase = (kh * 4 + hk) * RP + 38 + shift + ln;
        #pragma unroll
        for (int s = 0; s < 4; ++s) {
            const int fi = wave + 4 * s;
            if (fi < NFRAG) {
                bf16x8 Af = *reinterpret_cast<const bf16x8*>(&As[(cbase + 16 * fi) * 8]);
                #pragma unroll
                for (int n = 0; n < 4; ++n) {
                    acc[s][n] = __builtin_amdgcn_mfma_f32_16x16x32_bf16(Af, cur[n][0], acc[s][n], 0, 0, 0);
                    acc[s][n] = __builtin_amdgcn_mfma_f32_16x16x32_bf16(Af, cur[n][1], acc[s][n], 0, 0, 0);
                }
            }
        }
    };

    for (int tp = 0; tp < 13; ++tp) {   // statically-indexed double buffer
        body(2 * tp,     bA, bB);
        body(2 * tp + 1, bB, bA);
    }
    body(26, bA, bB);

    // ---- epilogue: store conv output + per-channel sum/sumsq
    float s1[4] = {0.f, 0.f, 0.f, 0.f};
    float s2[4] = {0.f, 0.f, 0.f, 0.f};
    #pragma unroll
    for (int s = 0; s < 4; ++s) {
        const int fi = wave + 4 * s;
        if (fi < NFRAG) {
            const int m0 = 38 + 16 * fi;
            #pragma unroll
            for (int r = 0; r < 4; ++r) {
                const int m  = m0 + hk * 4 + r;
                const int wp = m / PD;
                const int dp = m - wp * PD;
                if (dp >= 1 && dp <= 35 && wp >= 1 && wp <= TW) {
                    const int gw = w0 + wp - 1;
                    const int gd = dp - 1;
                    #pragma unroll
                    for (int n = 0; n < 4; ++n) {
                        const int co = n * 16 + ln;
                        const float vv = acc[s][n][r];
                        out[((((size_t)b * CO_ + co) * H_ + h) * W_ + gw) * D_ + gd] = vv;
                        s1[n] += vv;
                        s2[n] += vv * vv;
                    }
                }
            }
        }
    }
    #pragma unroll
    for (int n = 0; n < 4; ++n) {
        s1[n] += __shfl_xor(s1[n], 16);
        s1[n] += __shfl_xor(s1[n], 32);
        s2[n] += __shfl_xor(s2[n], 16);
        s2[n] += __shfl_xor(s2[n], 32);
    }
    if ((tid & 63) < 16) {
        #pragma unroll
        for (int n = 0; n < 4; ++n) {
            const int co = n * 16 + ln;
            atomicAdd(&stats[co * 2],     s1[n]);
            atomicAdd(&stats[co * 2 + 1], s2[n]);
        }
    }
}

// -------- Kernel 3: per-channel scale/shift ---------------------------------
__global__ void finalize_stats(const float* __restrict__ stats,
                               const float* __restrict__ gamma,
                               const float* __restrict__ beta,
                               float* __restrict__ ss) {
    const int c = threadIdx.x;
    if (c < CO_) {
        const float inv = 1.0f / (float)NPC;
        const float mean = stats[c * 2] * inv;
        const float var  = fmaf(-mean, mean, stats[c * 2 + 1] * inv);
        const float scale = gamma[c] * rsqrtf(var + 1e-5f);
        const float shift = fmaf(-mean, scale, beta[c]);
        ss[c * 2]     = scale;
        ss[c * 2 + 1] = shift;
    }
}

// -------- Kernel 4: BN apply + LeakyReLU, per-(b,c)-plane blocks ------------
// grid (79, B_*CO_), block 256; scale/shift are wave-uniform (SGPR), float4 IO
__global__ __launch_bounds__(256)
void bn_lrelu_kernel(float* __restrict__ out, const float* __restrict__ ss) {
    const int bc = blockIdx.y;
    const int c  = bc & (CO_ - 1);
    const float sc = ss[c * 2], sh = ss[c * 2 + 1];
    float4* p = reinterpret_cast<float4*>(out + (size_t)bc * PLANE);
    const int i0 = blockIdx.x * 1024 + threadIdx.x;
    #pragma unroll
    for (int k = 0; k < 4; ++k) {
        const int i = i0 + k * 256;
        if (i < PLANE / 4) {
            float4 v = p[i];
            v.x = fmaf(v.x, sc, sh);
            v.y = fmaf(v.y, sc, sh);
            v.z = fmaf(v.z, sc, sh);
            v.w = fmaf(v.w, sc, sh);
            v.x = v.x >= 0.0f ? v.x : NEG * v.x;
            v.y = v.y >= 0.0f ? v.y : NEG * v.y;
            v.z = v.z >= 0.0f ? v.z : NEG * v.z;
            v.w = v.w >= 0.0f ? v.w : NEG * v.w;
            p[i] = v;
        }
    }
}

extern "C" void kernel_launch(void* const* d_in, const int* in_sizes, int n_in,
                              void* d_out, int out_size, void* d_ws, size_t ws_size,
                              hipStream_t stream) {
    const float* x     = (const float*)d_in[0];
    const float* wg    = (const float*)d_in[1];
    // d_in[2] = bias: cancelled exactly by BatchNorm mean subtraction — unused.
    const float* gamma = (const float*)d_in[3];
    const float* beta  = (const float*)d_in[4];
    float* out   = (float*)d_out;

    char*  ws    = (char*)d_ws;
    float* stats = (float*)ws;                  // 128 f32 {sum, sumsq}
    float* ss    = (float*)(ws + 512);          // 128 f32 {scale, shift}
    short* Bg    = (short*)(ws + 1024);         // 27*2*2048 bf16 = 221184 B

    zero_stats<<<1, 128, 0, stream>>>(stats);
    prep_w<<<(27 * CO_ * CI_ + 255) / 256, 256, 0, stream>>>(wg, Bg);

    dim3 grid(W_ / TW, H_, B_);
    conv_mfma_kernel<<<grid, 256, 0, stream>>>(x, Bg, out, stats);

    finalize_stats<<<1, 64, 0, stream>>>(stats, gamma, beta, ss);

    dim3 grid4((PLANE / 4 + 1023) / 1024, B_ * CO_);
    bn_lrelu_kernel<<<grid4, 256, 0, stream>>>(out, ss);
}